// Round 1
// baseline (2307.876 us; speedup 1.0000x reference)
//
#include <hip/hip_runtime.h>
#include <math.h>

// Problem constants
// x:     [8, 512, 32, 32]        fp32
// W_qkv: [1536, 512, 3, 3]       fp32
// W_out: [512, 512, 1, 1]        fp32
// gamma/beta: [512]              fp32
// out:   [8, 512, 32, 32]        fp32
// G=8 heads, D=64 head dim, N=1024 seq (h*w)

#define SMOOTH 1e-4f
#define BN_EPS 1e-5f

// ---------------------------------------------------------------------------
// Kernel 1: 3x3 conv (implicit GEMM).  M=1536 (co), N=8192 (b*h*w), K=4608.
// Block: 256 thr. Tile: 64 co x 128 spatial (4 h-rows x 32 w), K-chunk 16 ci.
// Per thread: acc[8 co][4 h].
// ---------------------------------------------------------------------------
__global__ __launch_bounds__(256) void conv3x3_kernel(
    const float* __restrict__ x, const float* __restrict__ wq,
    float* __restrict__ qkv) {
  // W chunk: [t=ci*9+tap (144)][co (64)], stride 68 (16B-aligned rows per tco*8)
  __shared__ float Wl[144 * 68];
  // X chunk: [ci (16)][hh (6)][wi (36)], wi = w+1 (halo), cols 34..35 unused pad
  __shared__ float Xl[16 * 6 * 36];

  const int tid = threadIdx.x;
  const int tsp = tid & 31;   // w
  const int tco = tid >> 5;   // 0..7 -> co group of 8
  const int h0  = blockIdx.x * 4;
  const int co0 = blockIdx.y * 64;
  const int b   = blockIdx.z;

  float acc[8][4];
  for (int c = 0; c < 8; ++c)
    for (int s = 0; s < 4; ++s) acc[c][s] = 0.f;

  for (int ci0 = 0; ci0 < 512; ci0 += 16) {
    // Load W chunk: global layout co*4608 + ci*9 + tap, contiguous in t.
    for (int idx = tid; idx < 64 * 144; idx += 256) {
      int co = idx / 144;
      int t  = idx - co * 144;
      Wl[t * 68 + co] = wq[(size_t)(co0 + co) * 4608 + ci0 * 9 + t];
    }
    // Load X chunk with zero-padded halo.
    for (int idx = tid; idx < 16 * 6 * 34; idx += 256) {
      int wi  = idx % 34;
      int r   = idx / 34;
      int hh  = r % 6;
      int ci  = r / 6;
      int h   = h0 - 1 + hh;
      int w   = wi - 1;
      float v = 0.f;
      if (h >= 0 && h < 32 && (unsigned)w < 32u)
        v = x[((size_t)(b * 512 + ci0 + ci) * 32 + h) * 32 + w];
      Xl[(ci * 6 + hh) * 36 + wi] = v;
    }
    __syncthreads();

    for (int ci = 0; ci < 16; ++ci) {
#pragma unroll
      for (int ky = 0; ky < 3; ++ky) {
#pragma unroll
        for (int kx = 0; kx < 3; ++kx) {
          const int t = ci * 9 + ky * 3 + kx;
          float wv[8];
#pragma unroll
          for (int c = 0; c < 8; ++c) wv[c] = Wl[t * 68 + tco * 8 + c];
          float xv[4];
#pragma unroll
          for (int s = 0; s < 4; ++s) xv[s] = Xl[(ci * 6 + s + ky) * 36 + tsp + kx];
#pragma unroll
          for (int c = 0; c < 8; ++c)
#pragma unroll
            for (int s = 0; s < 4; ++s)
              acc[c][s] = fmaf(wv[c], xv[s], acc[c][s]);
        }
      }
    }
    __syncthreads();
  }

  for (int c = 0; c < 8; ++c)
    for (int s = 0; s < 4; ++s)
      qkv[(size_t)(b * 1536 + co0 + tco * 8 + c) * 1024 + (h0 + s) * 32 + tsp] =
          acc[c][s];
}

// ---------------------------------------------------------------------------
// Kernel 2: row norms  qn[b,g,i] = sqrt(sum_d q^2 + SMOOTH), same for k.
// ---------------------------------------------------------------------------
__global__ void norms_kernel(const float* __restrict__ qkv,
                             float* __restrict__ qn, float* __restrict__ kn) {
  int t = blockIdx.x * 256 + threadIdx.x;  // 65536 total
  int i = t & 1023;
  int bg = t >> 10;  // b*8+g
  int b = bg >> 3, g = bg & 7;
  const float* qbase = qkv + (size_t)(b * 1536 + g * 64) * 1024 + i;
  const float* kbase = qbase + (size_t)512 * 1024;
  float sq = 0.f, sk = 0.f;
  for (int d = 0; d < 64; ++d) {
    float qv = qbase[(size_t)d * 1024];
    float kv = kbase[(size_t)d * 1024];
    sq = fmaf(qv, qv, sq);
    sk = fmaf(kv, kv, sk);
  }
  qn[bg * 1024 + i] = sqrtf(sq + SMOOTH);
  kn[bg * 1024 + i] = sqrtf(sk + SMOOTH);
}

// ---------------------------------------------------------------------------
// Kernel 3: attention per (i-tile, g, b).
// S[i][j] = (q_i . k_j) / (qn_i*kn_j + SMOOTH);  O = S @ V  (no softmax).
// LDS: Q[64d][64i], K/S shared region [64][65], V[64d][64j].
// GEMM1 thread: i = ti+16a (broadcast side), j = tj+16c (coalesced side).
// GEMM2 thread: i = tj+16bi, dd = ti+16ad  -> coalesced stores over i.
// ---------------------------------------------------------------------------
__global__ __launch_bounds__(256) void attn_kernel(
    const float* __restrict__ qkv, const float* __restrict__ qn,
    const float* __restrict__ kn, float* __restrict__ ao) {
  __shared__ float Ql[64 * 64];
  __shared__ float KSl[64 * 65];  // K during GEMM1, then S (stride 65)
  __shared__ float Vl[64 * 64];

  const int tid = threadIdx.x;
  const int tj = tid & 15, ti = tid >> 4;
  const int i0 = blockIdx.x * 64;
  const int g = blockIdx.y, b = blockIdx.z;
  const int bg = b * 8 + g;
  const size_t base = (size_t)(b * 1536 + g * 64) * 1024;

  for (int idx = tid; idx < 4096; idx += 256) {
    int ii = idx & 63, d = idx >> 6;
    Ql[d * 64 + ii] = qkv[base + (size_t)d * 1024 + i0 + ii];
  }
  float qn_i[4];
  for (int a = 0; a < 4; ++a) qn_i[a] = qn[bg * 1024 + i0 + ti + 16 * a];

  float oacc[4][4];
  for (int a = 0; a < 4; ++a)
    for (int c = 0; c < 4; ++c) oacc[a][c] = 0.f;

  for (int jt = 0; jt < 16; ++jt) {
    const int j0 = jt * 64;
    __syncthreads();  // prior iter's KSl/Vl reads done (also covers Ql load)
    for (int idx = tid; idx < 4096; idx += 256) {
      int jj = idx & 63, d = idx >> 6;
      KSl[d * 65 + jj] = qkv[base + (size_t)(512 + d) * 1024 + j0 + jj];
      Vl[d * 64 + jj]  = qkv[base + (size_t)(1024 + d) * 1024 + j0 + jj];
    }
    __syncthreads();

    float sacc[4][4];
    for (int a = 0; a < 4; ++a)
      for (int c = 0; c < 4; ++c) sacc[a][c] = 0.f;
    for (int d = 0; d < 64; ++d) {
      float qv[4], kv[4];
#pragma unroll
      for (int a = 0; a < 4; ++a) qv[a] = Ql[d * 64 + ti + 16 * a];
#pragma unroll
      for (int c = 0; c < 4; ++c) kv[c] = KSl[d * 65 + tj + 16 * c];
#pragma unroll
      for (int a = 0; a < 4; ++a)
#pragma unroll
        for (int c = 0; c < 4; ++c) sacc[a][c] = fmaf(qv[a], kv[c], sacc[a][c]);
    }
    __syncthreads();  // K reads done; safe to overwrite region with S

    float kn_j[4];
    for (int c = 0; c < 4; ++c) kn_j[c] = kn[bg * 1024 + j0 + tj + 16 * c];
    for (int a = 0; a < 4; ++a)
      for (int c = 0; c < 4; ++c)
        KSl[(ti + 16 * a) * 65 + tj + 16 * c] =
            sacc[a][c] / (qn_i[a] * kn_j[c] + SMOOTH);
    __syncthreads();

    for (int j = 0; j < 64; ++j) {
      float sv[4], vv[4];
#pragma unroll
      for (int bi = 0; bi < 4; ++bi) sv[bi] = KSl[(tj + 16 * bi) * 65 + j];
#pragma unroll
      for (int ad = 0; ad < 4; ++ad) vv[ad] = Vl[(ti + 16 * ad) * 64 + j];
#pragma unroll
      for (int ad = 0; ad < 4; ++ad)
#pragma unroll
        for (int bi = 0; bi < 4; ++bi)
          oacc[ad][bi] = fmaf(sv[bi], vv[ad], oacc[ad][bi]);
    }
  }

  // Store O back in [b, c, p] layout: ao[b, g*64+dd, i]
  for (int ad = 0; ad < 4; ++ad)
    for (int bi = 0; bi < 4; ++bi)
      ao[(size_t)(b * 512 + g * 64 + ti + 16 * ad) * 1024 + i0 + tj + 16 * bi] =
          oacc[ad][bi];
}

// ---------------------------------------------------------------------------
// Kernel 4a: zero the BN stat accumulators (ws is poisoned 0xAA each launch)
// ---------------------------------------------------------------------------
__global__ void zero_stats(float* __restrict__ sums, float* __restrict__ sumsq) {
  int t = blockIdx.x * 256 + threadIdx.x;
  if (t < 512) {
    sums[t] = 0.f;
    sumsq[t] = 0.f;
  }
}

// ---------------------------------------------------------------------------
// Kernel 4: 1x1 conv GEMM (M=512 co, N=8192 p, K=512 ci) + per-channel
// sum/sumsq partials (shfl-reduce over 16-lane groups, then atomics).
// ---------------------------------------------------------------------------
__global__ __launch_bounds__(256) void conv1x1_kernel(
    const float* __restrict__ ao, const float* __restrict__ wout,
    float* __restrict__ y, float* __restrict__ sums,
    float* __restrict__ sumsq) {
  __shared__ float Wl[64 * 65];  // [ci][co]
  __shared__ float Bl[64 * 65];  // [ci][p]
  const int tid = threadIdx.x;
  const int tj = tid & 15, ti = tid >> 4;
  const int p0 = blockIdx.x * 64;
  const int co0 = blockIdx.y * 64;
  const int b = blockIdx.z;

  float acc[4][4];
  for (int a = 0; a < 4; ++a)
    for (int c = 0; c < 4; ++c) acc[a][c] = 0.f;

  for (int ci0 = 0; ci0 < 512; ci0 += 64) {
    __syncthreads();
    for (int idx = tid; idx < 4096; idx += 256) {
      int lo = idx & 63, hi = idx >> 6;
      Wl[lo * 65 + hi] = wout[(size_t)(co0 + hi) * 512 + ci0 + lo];
      Bl[hi * 65 + lo] = ao[(size_t)(b * 512 + ci0 + hi) * 1024 + p0 + lo];
    }
    __syncthreads();
    for (int ci = 0; ci < 64; ++ci) {
      float wv[4], bv[4];
#pragma unroll
      for (int a = 0; a < 4; ++a) wv[a] = Wl[ci * 65 + ti + 16 * a];
#pragma unroll
      for (int c = 0; c < 4; ++c) bv[c] = Bl[ci * 65 + tj + 16 * c];
#pragma unroll
      for (int a = 0; a < 4; ++a)
#pragma unroll
        for (int c = 0; c < 4; ++c) acc[a][c] = fmaf(wv[a], bv[c], acc[a][c]);
    }
  }

  float s1[4], s2[4];
  for (int a = 0; a < 4; ++a) { s1[a] = 0.f; s2[a] = 0.f; }
  for (int a = 0; a < 4; ++a)
    for (int c = 0; c < 4; ++c) {
      float v = acc[a][c];
      y[(size_t)(b * 512 + co0 + ti + 16 * a) * 1024 + p0 + tj + 16 * c] = v;
      s1[a] += v;
      s2[a] = fmaf(v, v, s2[a]);
    }
  for (int off = 8; off >= 1; off >>= 1)
    for (int a = 0; a < 4; ++a) {
      s1[a] += __shfl_down(s1[a], off, 16);
      s2[a] += __shfl_down(s2[a], off, 16);
    }
  if (tj == 0)
    for (int a = 0; a < 4; ++a) {
      atomicAdd(&sums[co0 + ti + 16 * a], s1[a]);
      atomicAdd(&sumsq[co0 + ti + 16 * a], s2[a]);
    }
}

// ---------------------------------------------------------------------------
// Kernel 5: BatchNorm (batch stats, biased var) + ReLU, float4.
// ---------------------------------------------------------------------------
__global__ void bn_kernel(const float* __restrict__ y,
                          const float* __restrict__ sums,
                          const float* __restrict__ sumsq,
                          const float* __restrict__ gamma,
                          const float* __restrict__ beta,
                          float* __restrict__ out) {
  int idx = blockIdx.x * 256 + threadIdx.x;  // one float4 each; 1048576 total
  int c = (idx >> 8) & 511;
  float4 v = ((const float4*)y)[idx];
  float mean = sums[c] * (1.f / 8192.f);
  float var = sumsq[c] * (1.f / 8192.f) - mean * mean;
  float sc = gamma[c] * rsqrtf(var + BN_EPS);
  float sh = beta[c] - mean * sc;
  float4 r;
  r.x = fmaxf(0.f, fmaf(v.x, sc, sh));
  r.y = fmaxf(0.f, fmaf(v.y, sc, sh));
  r.z = fmaxf(0.f, fmaf(v.z, sc, sh));
  r.w = fmaxf(0.f, fmaf(v.w, sc, sh));
  ((float4*)out)[idx] = r;
}

// ---------------------------------------------------------------------------
extern "C" void kernel_launch(void* const* d_in, const int* in_sizes, int n_in,
                              void* d_out, int out_size, void* d_ws,
                              size_t ws_size, hipStream_t stream) {
  const float* x     = (const float*)d_in[0];
  const float* wq    = (const float*)d_in[1];
  const float* wo    = (const float*)d_in[2];
  const float* gamma = (const float*)d_in[3];
  const float* beta  = (const float*)d_in[4];
  float* out = (float*)d_out;

  // Workspace layout (floats): qkv | qn | kn | ao | y | sums | sumsq
  float* ws    = (float*)d_ws;
  float* qkv   = ws;                                   // 8*1536*1024
  float* qn    = qkv + (size_t)8 * 1536 * 1024;        // 65536
  float* kn    = qn + 65536;                           // 65536
  float* ao    = kn + 65536;                           // 8*512*1024
  float* y     = ao + (size_t)8 * 512 * 1024;          // 8*512*1024
  float* sums  = y + (size_t)8 * 512 * 1024;           // 512
  float* sumsq = sums + 512;                           // 512

  conv3x3_kernel<<<dim3(8, 24, 8), 256, 0, stream>>>(x, wq, qkv);
  norms_kernel<<<dim3(256), 256, 0, stream>>>(qkv, qn, kn);
  zero_stats<<<dim3(2), 256, 0, stream>>>(sums, sumsq);
  attn_kernel<<<dim3(16, 8, 8), 256, 0, stream>>>(qkv, qn, kn, ao);
  conv1x1_kernel<<<dim3(16, 8, 8), 256, 0, stream>>>(ao, wo, y, sums, sumsq);
  bn_kernel<<<dim3(4096), 256, 0, stream>>>(y, sums, sumsq, gamma, beta, out);
}

// Round 2
// 716.835 us; speedup vs baseline: 3.2195x; 3.2195x over previous
//
#include <hip/hip_runtime.h>
#include <math.h>

// Problem constants
// x:     [8, 512, 32, 32]  fp32 | W_qkv: [1536, 512, 3, 3] fp32
// W_out: [512, 512, 1, 1]  fp32 | gamma/beta: [512] fp32
// out:   [8, 512, 32, 32]  fp32
// G=8 heads, D=64 head dim, N=1024 seq (h*w)

#define SMOOTH 1e-4f
#define BN_EPS 1e-5f

typedef __attribute__((ext_vector_type(8))) short bf16x8;
typedef __attribute__((ext_vector_type(4))) float f32x4;
typedef __attribute__((ext_vector_type(4))) unsigned int u32x4;

__device__ inline unsigned short bf16rne(float f) {
  unsigned int u = __float_as_uint(f);
  u += 0x7fff + ((u >> 16) & 1);
  return (unsigned short)(u >> 16);
}

// ---------------------------------------------------------------------------
// Repack W_qkv [co][ci][ky][kx] fp32 -> wqr [t][co][ci] bf16 (ci contiguous).
// ---------------------------------------------------------------------------
__global__ void repack_w(const float* __restrict__ wq,
                         unsigned short* __restrict__ wqr) {
  int idx = blockIdx.x * 256 + threadIdx.x;  // 9*1536*512 = 7077888
  int ci = idx & 511;
  int cot = idx >> 9;
  int co = cot % 1536;
  int t = cot / 1536;
  wqr[idx] = bf16rne(wq[((size_t)co * 512 + ci) * 9 + t]);
}

// ---------------------------------------------------------------------------
// Repack x [b][ci][h][w] fp32 -> xr [b][h][w][ci] bf16 (channel-last).
// ---------------------------------------------------------------------------
__global__ void repack_x(const float* __restrict__ x,
                         unsigned short* __restrict__ xr) {
  int idx = blockIdx.x * 256 + threadIdx.x;  // 8*1024*512 = 4194304
  int ci = idx & 511;
  int pb = idx >> 9;
  int p = pb & 1023;
  int b = pb >> 10;
  xr[idx] = bf16rne(x[((size_t)(b * 512 + ci)) * 1024 + p]);
}

// ---------------------------------------------------------------------------
// Kernel 1: 3x3 conv via bf16 MFMA implicit GEMM.
// M=1536(co) N=8192(b*p) K=4608(ci*9tap). Block 64co x 128sp (4h x 32w),
// 4 waves, wave tile 32co x 64n, mfma_f32_16x16x32_bf16.
// LDS: Wl[9][64co][32ci], Xl[6hh][34wi][32ci]  (ci contiguous -> ds_read_b128)
// ---------------------------------------------------------------------------
__global__ __launch_bounds__(256) void conv3x3_mfma(
    const unsigned short* __restrict__ wqr,
    const unsigned short* __restrict__ xr, float* __restrict__ qkv) {
  __shared__ __align__(16) unsigned short Wl[9 * 64 * 32];  // 36864 B
  __shared__ __align__(16) unsigned short Xl[6 * 34 * 32];  // 13056 B

  const int tid = threadIdx.x;
  const int lane = tid & 63;
  const int wave = tid >> 6;
  const int wco = (wave & 1) * 32;   // wave's co offset within tile
  const int wn = (wave >> 1) * 64;   // wave's spatial offset within tile
  const int l15 = lane & 15;
  const int quad = lane >> 4;
  const int k8 = quad * 8;           // k base within K=32 fragment
  const int h0 = blockIdx.x * 4;
  const int co0 = blockIdx.y * 64;
  const int b = blockIdx.z;

  f32x4 acc[2][4];
  for (int ma = 0; ma < 2; ++ma)
    for (int nb = 0; nb < 4; ++nb) acc[ma][nb] = (f32x4){0.f, 0.f, 0.f, 0.f};

  for (int ci0 = 0; ci0 < 512; ci0 += 32) {
    __syncthreads();
    // Stage W chunk: 9 taps x 64 co x 32 ci  (2304 x 16B)
    for (int idx = tid; idx < 2304; idx += 256) {
      int c4 = idx & 3;
      int co = (idx >> 2) & 63;
      int t = idx >> 8;
      u32x4 v = *(const u32x4*)(wqr +
                                ((size_t)(t * 1536 + co0 + co) * 512 + ci0 + c4 * 8));
      *(u32x4*)(Wl + (t * 64 + co) * 32 + c4 * 8) = v;
    }
    // Stage X chunk with halo: 6 hh x 34 wi x 32 ci  (816 x 16B)
    for (int idx = tid; idx < 816; idx += 256) {
      int c4 = idx & 3;
      int r = idx >> 2;
      int wi = r % 34;
      int hh = r / 34;
      int h = h0 - 1 + hh;
      int w = wi - 1;
      u32x4 v = {0u, 0u, 0u, 0u};
      if ((unsigned)h < 32u && (unsigned)w < 32u)
        v = *(const u32x4*)(xr +
                            ((size_t)((b * 32 + h) * 32 + w) * 512 + ci0 + c4 * 8));
      *(u32x4*)(Xl + (hh * 34 + wi) * 32 + c4 * 8) = v;
    }
    __syncthreads();

#pragma unroll
    for (int t = 0; t < 9; ++t) {
      const int ky = t / 3, kx = t - ky * 3;
      bf16x8 af[2], bfr[4];
#pragma unroll
      for (int ma = 0; ma < 2; ++ma)
        af[ma] = *(const bf16x8*)(Wl + (t * 64 + wco + ma * 16 + l15) * 32 + k8);
#pragma unroll
      for (int nb = 0; nb < 4; ++nb) {
        int n = wn + nb * 16 + l15;
        int hh = (n >> 5) + ky;
        int wi = (n & 31) + kx;
        bfr[nb] = *(const bf16x8*)(Xl + (hh * 34 + wi) * 32 + k8);
      }
#pragma unroll
      for (int ma = 0; ma < 2; ++ma)
#pragma unroll
        for (int nb = 0; nb < 4; ++nb)
          acc[ma][nb] = __builtin_amdgcn_mfma_f32_16x16x32_bf16(
              af[ma], bfr[nb], acc[ma][nb], 0, 0, 0);
    }
  }

  // Epilogue: C/D layout col(n)=lane&15, row(m)=quad*4+reg
#pragma unroll
  for (int ma = 0; ma < 2; ++ma)
#pragma unroll
    for (int nb = 0; nb < 4; ++nb)
#pragma unroll
      for (int r = 0; r < 4; ++r) {
        int co = co0 + wco + ma * 16 + quad * 4 + r;
        int n = wn + nb * 16 + l15;
        int p = (h0 + (n >> 5)) * 32 + (n & 31);
        qkv[(size_t)(b * 1536 + co) * 1024 + p] = acc[ma][nb][r];
      }
}

// ---------------------------------------------------------------------------
// Kernel 2: row norms  qn[b,g,i] = sqrt(sum_d q^2 + SMOOTH), same for k.
// ---------------------------------------------------------------------------
__global__ void norms_kernel(const float* __restrict__ qkv,
                             float* __restrict__ qn, float* __restrict__ kn) {
  int t = blockIdx.x * 256 + threadIdx.x;  // 65536 total
  int i = t & 1023;
  int bg = t >> 10;  // b*8+g
  int b = bg >> 3, g = bg & 7;
  const float* qbase = qkv + (size_t)(b * 1536 + g * 64) * 1024 + i;
  const float* kbase = qbase + (size_t)512 * 1024;
  float sq = 0.f, sk = 0.f;
  for (int d = 0; d < 64; ++d) {
    float qv = qbase[(size_t)d * 1024];
    float kv = kbase[(size_t)d * 1024];
    sq = fmaf(qv, qv, sq);
    sk = fmaf(kv, kv, sk);
  }
  qn[bg * 1024 + i] = sqrtf(sq + SMOOTH);
  kn[bg * 1024 + i] = sqrtf(sk + SMOOTH);
}

// ---------------------------------------------------------------------------
// Kernel 3: attention per (i-tile, g, b).  (unchanged from R1)
// ---------------------------------------------------------------------------
__global__ __launch_bounds__(256) void attn_kernel(
    const float* __restrict__ qkv, const float* __restrict__ qn,
    const float* __restrict__ kn, float* __restrict__ ao) {
  __shared__ float Ql[64 * 64];
  __shared__ float KSl[64 * 65];  // K during GEMM1, then S (stride 65)
  __shared__ float Vl[64 * 64];

  const int tid = threadIdx.x;
  const int tj = tid & 15, ti = tid >> 4;
  const int i0 = blockIdx.x * 64;
  const int g = blockIdx.y, b = blockIdx.z;
  const int bg = b * 8 + g;
  const size_t base = (size_t)(b * 1536 + g * 64) * 1024;

  for (int idx = tid; idx < 4096; idx += 256) {
    int ii = idx & 63, d = idx >> 6;
    Ql[d * 64 + ii] = qkv[base + (size_t)d * 1024 + i0 + ii];
  }
  float qn_i[4];
  for (int a = 0; a < 4; ++a) qn_i[a] = qn[bg * 1024 + i0 + ti + 16 * a];

  float oacc[4][4];
  for (int a = 0; a < 4; ++a)
    for (int c = 0; c < 4; ++c) oacc[a][c] = 0.f;

  for (int jt = 0; jt < 16; ++jt) {
    const int j0 = jt * 64;
    __syncthreads();
    for (int idx = tid; idx < 4096; idx += 256) {
      int jj = idx & 63, d = idx >> 6;
      KSl[d * 65 + jj] = qkv[base + (size_t)(512 + d) * 1024 + j0 + jj];
      Vl[d * 64 + jj] = qkv[base + (size_t)(1024 + d) * 1024 + j0 + jj];
    }
    __syncthreads();

    float sacc[4][4];
    for (int a = 0; a < 4; ++a)
      for (int c = 0; c < 4; ++c) sacc[a][c] = 0.f;
    for (int d = 0; d < 64; ++d) {
      float qv[4], kv[4];
#pragma unroll
      for (int a = 0; a < 4; ++a) qv[a] = Ql[d * 64 + ti + 16 * a];
#pragma unroll
      for (int c = 0; c < 4; ++c) kv[c] = KSl[d * 65 + tj + 16 * c];
#pragma unroll
      for (int a = 0; a < 4; ++a)
#pragma unroll
        for (int c = 0; c < 4; ++c) sacc[a][c] = fmaf(qv[a], kv[c], sacc[a][c]);
    }
    __syncthreads();

    float kn_j[4];
    for (int c = 0; c < 4; ++c) kn_j[c] = kn[bg * 1024 + j0 + tj + 16 * c];
    for (int a = 0; a < 4; ++a)
      for (int c = 0; c < 4; ++c)
        KSl[(ti + 16 * a) * 65 + tj + 16 * c] =
            sacc[a][c] / (qn_i[a] * kn_j[c] + SMOOTH);
    __syncthreads();

    for (int j = 0; j < 64; ++j) {
      float sv[4], vv[4];
#pragma unroll
      for (int bi = 0; bi < 4; ++bi) sv[bi] = KSl[(tj + 16 * bi) * 65 + j];
#pragma unroll
      for (int ad = 0; ad < 4; ++ad) vv[ad] = Vl[(ti + 16 * ad) * 64 + j];
#pragma unroll
      for (int ad = 0; ad < 4; ++ad)
#pragma unroll
        for (int bi = 0; bi < 4; ++bi)
          oacc[ad][bi] = fmaf(sv[bi], vv[ad], oacc[ad][bi]);
    }
  }

  for (int ad = 0; ad < 4; ++ad)
    for (int bi = 0; bi < 4; ++bi)
      ao[(size_t)(b * 512 + g * 64 + ti + 16 * ad) * 1024 + i0 + tj + 16 * bi] =
          oacc[ad][bi];
}

// ---------------------------------------------------------------------------
// Kernel 4a: zero the BN stat accumulators (ws is poisoned 0xAA each launch)
// ---------------------------------------------------------------------------
__global__ void zero_stats(float* __restrict__ sums, float* __restrict__ sumsq) {
  int t = blockIdx.x * 256 + threadIdx.x;
  if (t < 512) {
    sums[t] = 0.f;
    sumsq[t] = 0.f;
  }
}

// ---------------------------------------------------------------------------
// Kernel 4: 1x1 conv GEMM (M=512 co, N=8192 p, K=512 ci) + BN stats atomics.
// ---------------------------------------------------------------------------
__global__ __launch_bounds__(256) void conv1x1_kernel(
    const float* __restrict__ ao, const float* __restrict__ wout,
    float* __restrict__ y, float* __restrict__ sums,
    float* __restrict__ sumsq) {
  __shared__ float Wl[64 * 65];  // [ci][co]
  __shared__ float Bl[64 * 65];  // [ci][p]
  const int tid = threadIdx.x;
  const int tj = tid & 15, ti = tid >> 4;
  const int p0 = blockIdx.x * 64;
  const int co0 = blockIdx.y * 64;
  const int b = blockIdx.z;

  float acc[4][4];
  for (int a = 0; a < 4; ++a)
    for (int c = 0; c < 4; ++c) acc[a][c] = 0.f;

  for (int ci0 = 0; ci0 < 512; ci0 += 64) {
    __syncthreads();
    for (int idx = tid; idx < 4096; idx += 256) {
      int lo = idx & 63, hi = idx >> 6;
      Wl[lo * 65 + hi] = wout[(size_t)(co0 + hi) * 512 + ci0 + lo];
      Bl[hi * 65 + lo] = ao[(size_t)(b * 512 + ci0 + hi) * 1024 + p0 + lo];
    }
    __syncthreads();
    for (int ci = 0; ci < 64; ++ci) {
      float wv[4], bv[4];
#pragma unroll
      for (int a = 0; a < 4; ++a) wv[a] = Wl[ci * 65 + ti + 16 * a];
#pragma unroll
      for (int c = 0; c < 4; ++c) bv[c] = Bl[ci * 65 + tj + 16 * c];
#pragma unroll
      for (int a = 0; a < 4; ++a)
#pragma unroll
        for (int c = 0; c < 4; ++c) acc[a][c] = fmaf(wv[a], bv[c], acc[a][c]);
    }
  }

  float s1[4], s2[4];
  for (int a = 0; a < 4; ++a) { s1[a] = 0.f; s2[a] = 0.f; }
  for (int a = 0; a < 4; ++a)
    for (int c = 0; c < 4; ++c) {
      float v = acc[a][c];
      y[(size_t)(b * 512 + co0 + ti + 16 * a) * 1024 + p0 + tj + 16 * c] = v;
      s1[a] += v;
      s2[a] = fmaf(v, v, s2[a]);
    }
  for (int off = 8; off >= 1; off >>= 1)
    for (int a = 0; a < 4; ++a) {
      s1[a] += __shfl_down(s1[a], off, 16);
      s2[a] += __shfl_down(s2[a], off, 16);
    }
  if (tj == 0)
    for (int a = 0; a < 4; ++a) {
      atomicAdd(&sums[co0 + ti + 16 * a], s1[a]);
      atomicAdd(&sumsq[co0 + ti + 16 * a], s2[a]);
    }
}

// ---------------------------------------------------------------------------
// Kernel 5: BatchNorm (batch stats, biased var) + ReLU, float4.
// ---------------------------------------------------------------------------
__global__ void bn_kernel(const float* __restrict__ y,
                          const float* __restrict__ sums,
                          const float* __restrict__ sumsq,
                          const float* __restrict__ gamma,
                          const float* __restrict__ beta,
                          float* __restrict__ out) {
  int idx = blockIdx.x * 256 + threadIdx.x;  // one float4 each; 1048576 total
  int c = (idx >> 8) & 511;
  float4 v = ((const float4*)y)[idx];
  float mean = sums[c] * (1.f / 8192.f);
  float var = sumsq[c] * (1.f / 8192.f) - mean * mean;
  float sc = gamma[c] * rsqrtf(var + BN_EPS);
  float sh = beta[c] - mean * sc;
  float4 r;
  r.x = fmaxf(0.f, fmaf(v.x, sc, sh));
  r.y = fmaxf(0.f, fmaf(v.y, sc, sh));
  r.z = fmaxf(0.f, fmaf(v.z, sc, sh));
  r.w = fmaxf(0.f, fmaf(v.w, sc, sh));
  ((float4*)out)[idx] = r;
}

// ---------------------------------------------------------------------------
extern "C" void kernel_launch(void* const* d_in, const int* in_sizes, int n_in,
                              void* d_out, int out_size, void* d_ws,
                              size_t ws_size, hipStream_t stream) {
  const float* x = (const float*)d_in[0];
  const float* wq = (const float*)d_in[1];
  const float* wo = (const float*)d_in[2];
  const float* gamma = (const float*)d_in[3];
  const float* beta = (const float*)d_in[4];
  float* out = (float*)d_out;

  // Workspace layout (floats): qkv | qn | kn | ao | y | sums | sumsq
  // wqr (14.2 MB bf16) aliases ao (16.8 MB): ao written only after conv3x3.
  // xr  (8.4 MB bf16)  aliases y  (16.8 MB): y  written only in conv1x1.
  float* ws = (float*)d_ws;
  float* qkv = ws;                             // 8*1536*1024
  float* qn = qkv + (size_t)8 * 1536 * 1024;   // 65536
  float* kn = qn + 65536;                      // 65536
  float* ao = kn + 65536;                      // 8*512*1024
  float* y = ao + (size_t)8 * 512 * 1024;      // 8*512*1024
  float* sums = y + (size_t)8 * 512 * 1024;    // 512
  float* sumsq = sums + 512;                   // 512
  unsigned short* wqr = (unsigned short*)ao;   // [9][1536][512] bf16
  unsigned short* xr = (unsigned short*)y;     // [8][32][32][512] bf16

  repack_w<<<dim3(27648), 256, 0, stream>>>(wq, wqr);
  repack_x<<<dim3(16384), 256, 0, stream>>>(x, xr);
  conv3x3_mfma<<<dim3(8, 24, 8), 256, 0, stream>>>(wqr, xr, qkv);
  norms_kernel<<<dim3(256), 256, 0, stream>>>(qkv, qn, kn);
  zero_stats<<<dim3(2), 256, 0, stream>>>(sums, sumsq);
  attn_kernel<<<dim3(16, 8, 8), 256, 0, stream>>>(qkv, qn, kn, ao);
  conv1x1_kernel<<<dim3(16, 8, 8), 256, 0, stream>>>(ao, wo, y, sums, sumsq);
  bn_kernel<<<dim3(4096), 256, 0, stream>>>(y, sums, sumsq, gamma, beta, out);
}

// Round 3
// 356.722 us; speedup vs baseline: 6.4697x; 2.0095x over previous
//
#include <hip/hip_runtime.h>
#include <math.h>

// x: [8,512,32,32] fp32 | W_qkv: [1536,512,3,3] fp32 | W_out: [512,512,1,1]
// gamma/beta: [512] | out: [8,512,32,32] fp32
// G=8 heads, D=64 head dim, N=1024 seq (h*w), B=8

#define SMOOTH 1e-4f
#define BN_EPS 1e-5f

typedef __attribute__((ext_vector_type(8))) short bf16x8;
typedef __attribute__((ext_vector_type(4))) float f32x4;
typedef __attribute__((ext_vector_type(4))) unsigned int u32x4;
typedef __attribute__((ext_vector_type(4))) unsigned short u16x4;

__device__ inline unsigned short bf16rne(float f) {
  unsigned int u = __float_as_uint(f);
  u += 0x7fff + ((u >> 16) & 1);
  return (unsigned short)(u >> 16);
}
__device__ inline float b2f(unsigned short u) {
  return __uint_as_float((unsigned int)u << 16);
}

// ---------------------------------------------------------------------------
// Repack W_qkv [co][ci][3][3] fp32 -> wqr [t][co][ci] bf16 (ci contiguous).
// ---------------------------------------------------------------------------
__global__ void repack_w(const float* __restrict__ wq,
                         unsigned short* __restrict__ wqr) {
  int idx = blockIdx.x * 256 + threadIdx.x;  // 9*1536*512
  int ci = idx & 511;
  int cot = idx >> 9;
  int co = cot % 1536;
  int t = cot / 1536;
  wqr[idx] = bf16rne(wq[((size_t)co * 512 + ci) * 9 + t]);
}

// Repack x [b][ci][h][w] fp32 -> xr [b][h][w][ci] bf16 (channel-last).
__global__ void repack_x(const float* __restrict__ x,
                         unsigned short* __restrict__ xr) {
  int idx = blockIdx.x * 256 + threadIdx.x;  // 8*1024*512
  int ci = idx & 511;
  int pb = idx >> 9;
  int p = pb & 1023;
  int b = pb >> 10;
  xr[idx] = bf16rne(x[((size_t)(b * 512 + ci)) * 1024 + p]);
}

// Repack W_out fp32 -> bf16 (layout already [co][ci]).
__global__ void repack_wo(const float* __restrict__ wo,
                          unsigned short* __restrict__ wor) {
  int idx = blockIdx.x * 256 + threadIdx.x;  // 262144
  wor[idx] = bf16rne(wo[idx]);
}

// ---------------------------------------------------------------------------
// Kernel 1: 3x3 conv bf16 MFMA implicit GEMM. Epilogue writes bf16 directly:
//   q,k sections -> qt/kt[bg][i][d]  (d contiguous: attn A/B-frag layout)
//   v section    -> vt[bg][d][j]     (j contiguous: attn GEMM2 B layout)
// ---------------------------------------------------------------------------
__global__ __launch_bounds__(256) void conv3x3_mfma(
    const unsigned short* __restrict__ wqr,
    const unsigned short* __restrict__ xr,
    unsigned short* __restrict__ qt, unsigned short* __restrict__ kt,
    unsigned short* __restrict__ vt) {
  __shared__ __align__(16) unsigned short Wl[9 * 64 * 32];  // 36864 B
  __shared__ __align__(16) unsigned short Xl[6 * 34 * 32];  // 13056 B

  const int tid = threadIdx.x;
  const int lane = tid & 63;
  const int wave = tid >> 6;
  const int wco = (wave & 1) * 32;
  const int wn = (wave >> 1) * 64;
  const int l15 = lane & 15;
  const int quad = lane >> 4;
  const int k8 = quad * 8;
  const int h0 = blockIdx.x * 4;
  const int co0 = blockIdx.y * 64;
  const int b = blockIdx.z;

  f32x4 acc[2][4];
  for (int ma = 0; ma < 2; ++ma)
    for (int nb = 0; nb < 4; ++nb) acc[ma][nb] = (f32x4){0.f, 0.f, 0.f, 0.f};

  for (int ci0 = 0; ci0 < 512; ci0 += 32) {
    __syncthreads();
    for (int idx = tid; idx < 2304; idx += 256) {
      int c4 = idx & 3;
      int co = (idx >> 2) & 63;
      int t = idx >> 8;
      u32x4 v = *(const u32x4*)(wqr +
                                ((size_t)(t * 1536 + co0 + co) * 512 + ci0 + c4 * 8));
      *(u32x4*)(Wl + (t * 64 + co) * 32 + c4 * 8) = v;
    }
    for (int idx = tid; idx < 816; idx += 256) {
      int c4 = idx & 3;
      int r = idx >> 2;
      int wi = r % 34;
      int hh = r / 34;
      int h = h0 - 1 + hh;
      int w = wi - 1;
      u32x4 v = {0u, 0u, 0u, 0u};
      if ((unsigned)h < 32u && (unsigned)w < 32u)
        v = *(const u32x4*)(xr +
                            ((size_t)((b * 32 + h) * 32 + w) * 512 + ci0 + c4 * 8));
      *(u32x4*)(Xl + (hh * 34 + wi) * 32 + c4 * 8) = v;
    }
    __syncthreads();

#pragma unroll
    for (int t = 0; t < 9; ++t) {
      const int ky = t / 3, kx = t - ky * 3;
      bf16x8 af[2], bfr[4];
#pragma unroll
      for (int ma = 0; ma < 2; ++ma)
        af[ma] = *(const bf16x8*)(Wl + (t * 64 + wco + ma * 16 + l15) * 32 + k8);
#pragma unroll
      for (int nb = 0; nb < 4; ++nb) {
        int n = wn + nb * 16 + l15;
        int hh = (n >> 5) + ky;
        int wi = (n & 31) + kx;
        bfr[nb] = *(const bf16x8*)(Xl + (hh * 34 + wi) * 32 + k8);
      }
#pragma unroll
      for (int ma = 0; ma < 2; ++ma)
#pragma unroll
        for (int nb = 0; nb < 4; ++nb)
          acc[ma][nb] = __builtin_amdgcn_mfma_f32_16x16x32_bf16(
              af[ma], bfr[nb], acc[ma][nb], 0, 0, 0);
    }
  }

  // Epilogue: C/D layout col(n)=lane&15, row(m)=quad*4+reg. co0 is 64-aligned
  // so the whole block is one (section, head) pair.
  const int sec = co0 >> 9;
  const int g = (co0 & 511) >> 6;
  const int bg = b * 8 + g;
  if (sec < 2) {
    unsigned short* dst = (sec == 0) ? qt : kt;
#pragma unroll
    for (int ma = 0; ma < 2; ++ma)
#pragma unroll
      for (int nb = 0; nb < 4; ++nb) {
        int n = wn + nb * 16 + l15;
        int p = (h0 + (n >> 5)) * 32 + (n & 31);
        int db = wco + ma * 16 + quad * 4;
        u16x4 pk;
#pragma unroll
        for (int r = 0; r < 4; ++r) pk[r] = bf16rne(acc[ma][nb][r]);
        *(u16x4*)(dst + ((size_t)bg * 1024 + p) * 64 + db) = pk;
      }
  } else {
#pragma unroll
    for (int ma = 0; ma < 2; ++ma)
#pragma unroll
      for (int nb = 0; nb < 4; ++nb) {
        int n = wn + nb * 16 + l15;
        int p = (h0 + (n >> 5)) * 32 + (n & 31);
#pragma unroll
        for (int r = 0; r < 4; ++r) {
          int d = wco + ma * 16 + quad * 4 + r;
          vt[((size_t)bg * 64 + d) * 1024 + p] = bf16rne(acc[ma][nb][r]);
        }
      }
  }
}

// ---------------------------------------------------------------------------
// Kernel 2: row norms from bf16 qt/kt ([bg][i][64] d-contiguous).
// ---------------------------------------------------------------------------
__global__ void norms_kernel(const unsigned short* __restrict__ qt,
                             const unsigned short* __restrict__ kt,
                             float* __restrict__ qn, float* __restrict__ kn) {
  int t = blockIdx.x * 256 + threadIdx.x;  // 65536 = bg*1024 + i
  const unsigned short* qp = qt + (size_t)t * 64;
  const unsigned short* kp = kt + (size_t)t * 64;
  float sq = 0.f, sk = 0.f;
  for (int c = 0; c < 64; c += 8) {
    bf16x8 qv = *(const bf16x8*)(qp + c);
    bf16x8 kv = *(const bf16x8*)(kp + c);
#pragma unroll
    for (int e = 0; e < 8; ++e) {
      float q = b2f((unsigned short)qv[e]);
      float k = b2f((unsigned short)kv[e]);
      sq = fmaf(q, q, sq);
      sk = fmaf(k, k, sk);
    }
  }
  qn[t] = sqrtf(sq + SMOOTH);
  kn[t] = sqrtf(sk + SMOOTH);
}

// ---------------------------------------------------------------------------
// Kernel 3: attention, bf16 MFMA. Block = 128 i x (b,g); 4 waves, 32 i each.
// Q frags in registers (loop-invariant). Per 64-j tile: stage K/V in LDS,
// GEMM1 -> fp32 S -> normalize -> bf16 to wave-private LDS -> GEMM2.
// Writes aob[b][p][c] bf16 (ci-contiguous = conv1x1 B-frag layout).
// ---------------------------------------------------------------------------
__global__ __launch_bounds__(256) void attn_mfma(
    const unsigned short* __restrict__ qt, const unsigned short* __restrict__ kt,
    const unsigned short* __restrict__ vt, const float* __restrict__ qn,
    const float* __restrict__ kn, unsigned short* __restrict__ aob) {
  __shared__ __align__(16) unsigned short Kl[64 * 72];   // [j][d] rows 144B
  __shared__ __align__(16) unsigned short Vl[64 * 72];   // [d][j]
  __shared__ __align__(16) unsigned short Sl[128 * 72];  // [i][j] (per-wave)

  const int tid = threadIdx.x;
  const int lane = tid & 63, wave = tid >> 6;
  const int l15 = lane & 15, quad = lane >> 4;
  const int bg = blockIdx.x;       // fastest -> same-bg blocks share XCD L2
  const int i0 = blockIdx.y * 128;
  const int iw = i0 + wave * 32;
  const int b = bg >> 3, g = bg & 7;

  bf16x8 qf[2][2];
#pragma unroll
  for (int ma = 0; ma < 2; ++ma)
#pragma unroll
    for (int ks = 0; ks < 2; ++ks)
      qf[ma][ks] = *(const bf16x8*)(
          qt + ((size_t)bg * 1024 + iw + ma * 16 + l15) * 64 + ks * 32 + quad * 8);

  float qn_i[2][4];
#pragma unroll
  for (int ma = 0; ma < 2; ++ma)
#pragma unroll
    for (int r = 0; r < 4; ++r)
      qn_i[ma][r] = qn[bg * 1024 + iw + ma * 16 + quad * 4 + r];

  f32x4 oacc[2][4];
  for (int mf = 0; mf < 2; ++mf)
    for (int nf = 0; nf < 4; ++nf) oacc[mf][nf] = (f32x4){0.f, 0.f, 0.f, 0.f};

  unsigned short* Sw = Sl + wave * 32 * 72;

  for (int jt = 0; jt < 16; ++jt) {
    const int j0 = jt * 64;
    __syncthreads();
    for (int idx = tid; idx < 512; idx += 256) {
      int c8 = idx & 7, row = idx >> 3;
      *(u32x4*)(Kl + row * 72 + c8 * 8) =
          *(const u32x4*)(kt + ((size_t)bg * 1024 + j0 + row) * 64 + c8 * 8);
      *(u32x4*)(Vl + row * 72 + c8 * 8) =
          *(const u32x4*)(vt + ((size_t)bg * 64 + row) * 1024 + j0 + c8 * 8);
    }
    __syncthreads();

    f32x4 sacc[2][4];
    for (int ma = 0; ma < 2; ++ma)
      for (int nb = 0; nb < 4; ++nb) sacc[ma][nb] = (f32x4){0.f, 0.f, 0.f, 0.f};
#pragma unroll
    for (int ks = 0; ks < 2; ++ks) {
      bf16x8 kf[4];
#pragma unroll
      for (int nb = 0; nb < 4; ++nb)
        kf[nb] = *(const bf16x8*)(Kl + (l15 + 16 * nb) * 72 + ks * 32 + quad * 8);
#pragma unroll
      for (int ma = 0; ma < 2; ++ma)
#pragma unroll
        for (int nb = 0; nb < 4; ++nb)
          sacc[ma][nb] = __builtin_amdgcn_mfma_f32_16x16x32_bf16(
              qf[ma][ks], kf[nb], sacc[ma][nb], 0, 0, 0);
    }

    float kn_j[4];
#pragma unroll
    for (int nb = 0; nb < 4; ++nb) kn_j[nb] = kn[bg * 1024 + j0 + l15 + 16 * nb];
#pragma unroll
    for (int ma = 0; ma < 2; ++ma)
#pragma unroll
      for (int nb = 0; nb < 4; ++nb)
#pragma unroll
        for (int r = 0; r < 4; ++r) {
          float s = sacc[ma][nb][r] / (qn_i[ma][r] * kn_j[nb] + SMOOTH);
          Sw[(ma * 16 + quad * 4 + r) * 72 + l15 + 16 * nb] = bf16rne(s);
        }
    // Sw is wave-private: no __syncthreads needed; lgkmcnt orders write->read.
#pragma unroll
    for (int ks2 = 0; ks2 < 2; ++ks2) {
      bf16x8 sa[2];
#pragma unroll
      for (int mf = 0; mf < 2; ++mf)
        sa[mf] = *(const bf16x8*)(Sw + (mf * 16 + l15) * 72 + ks2 * 32 + quad * 8);
#pragma unroll
      for (int nf = 0; nf < 4; ++nf) {
        bf16x8 vb = *(const bf16x8*)(Vl + (l15 + 16 * nf) * 72 + ks2 * 32 + quad * 8);
#pragma unroll
        for (int mf = 0; mf < 2; ++mf)
          oacc[mf][nf] = __builtin_amdgcn_mfma_f32_16x16x32_bf16(
              sa[mf], vb, oacc[mf][nf], 0, 0, 0);
      }
    }
  }

#pragma unroll
  for (int mf = 0; mf < 2; ++mf)
#pragma unroll
    for (int nf = 0; nf < 4; ++nf)
#pragma unroll
      for (int r = 0; r < 4; ++r) {
        int i = iw + mf * 16 + quad * 4 + r;
        int d = l15 + 16 * nf;
        aob[((size_t)(b * 1024) + i) * 512 + g * 64 + d] = bf16rne(oacc[mf][nf][r]);
      }
}

// ---------------------------------------------------------------------------
// Kernel 4a: zero BN stat accumulators.
// ---------------------------------------------------------------------------
__global__ void zero_stats(float* __restrict__ sums, float* __restrict__ sumsq) {
  int t = blockIdx.x * 256 + threadIdx.x;
  if (t < 512) {
    sums[t] = 0.f;
    sumsq[t] = 0.f;
  }
}

// ---------------------------------------------------------------------------
// Kernel 4: 1x1 conv bf16 MFMA (M=512co, N=8192p, K=512ci) + BN stats.
// Block 64co x 128p, 4 waves (32co x 64p), K-chunks of 32.
// ---------------------------------------------------------------------------
__global__ __launch_bounds__(256) void conv1x1_mfma(
    const unsigned short* __restrict__ wor, const unsigned short* __restrict__ aob,
    float* __restrict__ y, float* __restrict__ sums, float* __restrict__ sumsq) {
  __shared__ __align__(16) unsigned short Wl[64 * 40];   // [co][ci] rows 80B
  __shared__ __align__(16) unsigned short Bl[128 * 40];  // [p][ci]

  const int tid = threadIdx.x;
  const int lane = tid & 63, wave = tid >> 6;
  const int l15 = lane & 15, quad = lane >> 4;
  const int wco = (wave & 1) * 32;
  const int wn = (wave >> 1) * 64;
  const int p0 = blockIdx.x * 128;
  const int co0 = blockIdx.y * 64;
  const int b = blockIdx.z;

  f32x4 acc[2][4];
  for (int ma = 0; ma < 2; ++ma)
    for (int nb = 0; nb < 4; ++nb) acc[ma][nb] = (f32x4){0.f, 0.f, 0.f, 0.f};

  for (int ci0 = 0; ci0 < 512; ci0 += 32) {
    __syncthreads();
    {
      int c8 = tid & 3, co = tid >> 2;
      *(u32x4*)(Wl + co * 40 + c8 * 8) =
          *(const u32x4*)(wor + (size_t)(co0 + co) * 512 + ci0 + c8 * 8);
    }
#pragma unroll
    for (int it = 0; it < 2; ++it) {
      int idx = tid + it * 256;
      int c8 = idx & 3, p = idx >> 2;
      *(u32x4*)(Bl + p * 40 + c8 * 8) =
          *(const u32x4*)(aob + ((size_t)(b * 1024) + p0 + p) * 512 + ci0 + c8 * 8);
    }
    __syncthreads();

    bf16x8 af[2];
#pragma unroll
    for (int ma = 0; ma < 2; ++ma)
      af[ma] = *(const bf16x8*)(Wl + (wco + ma * 16 + l15) * 40 + quad * 8);
#pragma unroll
    for (int nb = 0; nb < 4; ++nb) {
      bf16x8 bfr = *(const bf16x8*)(Bl + (wn + nb * 16 + l15) * 40 + quad * 8);
#pragma unroll
      for (int ma = 0; ma < 2; ++ma)
        acc[ma][nb] = __builtin_amdgcn_mfma_f32_16x16x32_bf16(
            af[ma], bfr, acc[ma][nb], 0, 0, 0);
    }
  }

#pragma unroll
  for (int ma = 0; ma < 2; ++ma)
#pragma unroll
    for (int r = 0; r < 4; ++r) {
      int co = co0 + wco + ma * 16 + quad * 4 + r;
      float s1 = 0.f, s2 = 0.f;
#pragma unroll
      for (int nb = 0; nb < 4; ++nb) {
        float v = acc[ma][nb][r];
        y[((size_t)(b * 512) + co) * 1024 + p0 + wn + nb * 16 + l15] = v;
        s1 += v;
        s2 = fmaf(v, v, s2);
      }
      for (int off = 8; off >= 1; off >>= 1) {
        s1 += __shfl_down(s1, off, 16);
        s2 += __shfl_down(s2, off, 16);
      }
      if (l15 == 0) {
        atomicAdd(&sums[co], s1);
        atomicAdd(&sumsq[co], s2);
      }
    }
}

// ---------------------------------------------------------------------------
// Kernel 5: BatchNorm (batch stats, biased var) + ReLU, float4.
// ---------------------------------------------------------------------------
__global__ void bn_kernel(const float* __restrict__ y,
                          const float* __restrict__ sums,
                          const float* __restrict__ sumsq,
                          const float* __restrict__ gamma,
                          const float* __restrict__ beta,
                          float* __restrict__ out) {
  int idx = blockIdx.x * 256 + threadIdx.x;  // 1048576 float4s
  int c = (idx >> 8) & 511;
  float4 v = ((const float4*)y)[idx];
  float mean = sums[c] * (1.f / 8192.f);
  float var = sumsq[c] * (1.f / 8192.f) - mean * mean;
  float sc = gamma[c] * rsqrtf(var + BN_EPS);
  float sh = beta[c] - mean * sc;
  float4 r;
  r.x = fmaxf(0.f, fmaf(v.x, sc, sh));
  r.y = fmaxf(0.f, fmaf(v.y, sc, sh));
  r.z = fmaxf(0.f, fmaf(v.z, sc, sh));
  r.w = fmaxf(0.f, fmaf(v.w, sc, sh));
  ((float4*)out)[idx] = r;
}

// ---------------------------------------------------------------------------
extern "C" void kernel_launch(void* const* d_in, const int* in_sizes, int n_in,
                              void* d_out, int out_size, void* d_ws,
                              size_t ws_size, hipStream_t stream) {
  const float* x = (const float*)d_in[0];
  const float* wq = (const float*)d_in[1];
  const float* wo = (const float*)d_in[2];
  const float* gamma = (const float*)d_in[3];
  const float* beta = (const float*)d_in[4];
  float* out = (float*)d_out;

  // Workspace layout (~74 MB, all 16B aligned)
  unsigned short* qt = (unsigned short*)d_ws;          // [64][1024][64]
  unsigned short* kt = qt + (size_t)4194304;
  unsigned short* vt = kt + (size_t)4194304;           // [64][64][1024]
  unsigned short* aob = vt + (size_t)4194304;          // [8][1024][512]
  unsigned short* wqr = aob + (size_t)4194304;         // [9][1536][512]
  unsigned short* wor = wqr + (size_t)7077888;         // [512][512]
  unsigned short* xr = wor + (size_t)262144;           // [8][1024][512]
  float* qn = (float*)(xr + (size_t)4194304);          // [64][1024]
  float* kn = qn + 65536;
  float* y = kn + 65536;                               // [8][512][1024] fp32
  float* sums = y + (size_t)4194304;
  float* sumsq = sums + 512;

  repack_w<<<dim3(27648), 256, 0, stream>>>(wq, wqr);
  repack_x<<<dim3(16384), 256, 0, stream>>>(x, xr);
  repack_wo<<<dim3(1024), 256, 0, stream>>>(wo, wor);
  conv3x3_mfma<<<dim3(8, 24, 8), 256, 0, stream>>>(wqr, xr, qt, kt, vt);
  norms_kernel<<<dim3(256), 256, 0, stream>>>(qt, kt, qn, kn);
  zero_stats<<<dim3(2), 256, 0, stream>>>(sums, sumsq);
  attn_mfma<<<dim3(64, 8), 256, 0, stream>>>(qt, kt, vt, qn, kn, aob);
  conv1x1_mfma<<<dim3(8, 8, 8), 256, 0, stream>>>(wor, aob, y, sums, sumsq);
  bn_kernel<<<dim3(4096), 256, 0, stream>>>(y, sums, sumsq, gamma, beta, out);
}